// Round 7
// baseline (64.197 us; speedup 1.0000x reference)
//
#include <hip/hip_runtime.h>

#define N_SAMPLES 128
#define NBLK 2048   // persistent grid: 8 blocks/CU

// DPP ctrl encodings (gfx9/CDNA)
#define DPP_ROW_SHR1  0x111
#define DPP_ROW_SHR2  0x112
#define DPP_ROW_SHR4  0x114
#define DPP_ROW_SHR8  0x118
#define DPP_ROW_ROR4  0x124
#define DPP_ROW_ROR8  0x128
#define DPP_BCAST15   0x142  // broadcast lane15 of each row to the NEXT row
#define DPP_QUAD_XOR1 0xB1   // quad_perm [1,0,3,2]
#define DPP_QUAD_XOR2 0x4E   // quad_perm [2,3,0,1]

template <int CTRL, int ROWMASK>
__device__ __forceinline__ float dpp_shift_id1(float src) {
    int s = __builtin_bit_cast(int, src);
    int o = __builtin_bit_cast(int, 1.0f);
    int r = __builtin_amdgcn_update_dpp(o, s, CTRL, ROWMASK, 0xF, false);
    return __builtin_bit_cast(float, r);
}

template <int CTRL>
__device__ __forceinline__ float dpp_mov(float src) {
    int r = __builtin_amdgcn_mov_dpp(__builtin_bit_cast(int, src), CTRL, 0xF, 0xF, true);
    return __builtin_bit_cast(float, r);
}

__device__ __forceinline__ float row16_sum(float x) {
    x += dpp_mov<DPP_QUAD_XOR1>(x);
    x += dpp_mov<DPP_QUAD_XOR2>(x);
    x += dpp_mov<DPP_ROW_ROR4>(x);
    x += dpp_mov<DPP_ROW_ROR8>(x);
    return x;
}

__device__ __forceinline__ float swz_xor16(float x) {
    int r = __builtin_amdgcn_ds_swizzle(__builtin_bit_cast(int, x), 0x401F);
    return __builtin_bit_cast(float, r);
}

__device__ __forceinline__ void compute_store(
    float4 d, float4 s, float4 q0, float4 q1, float4 q2,
    int ray, int n_rays, int llane,
    float* __restrict__ out_color, float* __restrict__ out_depth)
{
    // delta[i] = d[i+1] - d[i]; sample 127 padded with 1e10
    float dnext  = __shfl_down(d.x, 1, 32);
    float delta0 = d.y - d.x;
    float delta1 = d.z - d.y;
    float delta2 = d.w - d.z;
    float delta3 = (llane == 31) ? 1e10f : (dnext - d.w);

    const float EPS = 1e-10f;
    float e0 = __expf(-fmaxf(s.x, 0.0f) * delta0);
    float e1 = __expf(-fmaxf(s.y, 0.0f) * delta1);
    float e2 = __expf(-fmaxf(s.z, 0.0f) * delta2);
    float e3 = __expf(-fmaxf(s.w, 0.0f) * delta3);
    float a0 = 1.0f - e0, a1 = 1.0f - e1, a2 = 1.0f - e2, a3 = 1.0f - e3;
    float t0 = e0 + EPS, t1 = e1 + EPS, t2 = e2 + EPS, t3 = e3 + EPS;

    // 32-lane exclusive multiplicative scan, all DPP
    float rowincl = t0 * t1 * t2 * t3;
    rowincl *= dpp_shift_id1<DPP_ROW_SHR1, 0xF>(rowincl);
    rowincl *= dpp_shift_id1<DPP_ROW_SHR2, 0xF>(rowincl);
    rowincl *= dpp_shift_id1<DPP_ROW_SHR4, 0xF>(rowincl);
    rowincl *= dpp_shift_id1<DPP_ROW_SHR8, 0xF>(rowincl);  // row-16 inclusive
    // BCAST15 writes NEXT row (row2 <- lane31!); row_mask=0xA keeps rows 0,2 at 1.0
    float b       = dpp_shift_id1<DPP_BCAST15, 0xA>(rowincl);
    float rowexcl = dpp_shift_id1<DPP_ROW_SHR1, 0xF>(rowincl);
    float excl    = rowexcl * b;   // exact 32-lane exclusive prefix

    float w0 = a0 * excl;
    float pre1 = excl * t0;
    float w1 = a1 * pre1;
    float pre2 = pre1 * t1;
    float w2 = a2 * pre2;
    float w3 = a3 * pre2 * t2;

    auto sg = [](float x) { return 1.0f / (1.0f + __expf(-x)); };

    float c0 = w0 * sg(q0.x) + w1 * sg(q0.w) + w2 * sg(q1.z) + w3 * sg(q2.y);
    float c1 = w0 * sg(q0.y) + w1 * sg(q1.x) + w2 * sg(q1.w) + w3 * sg(q2.z);
    float c2 = w0 * sg(q0.z) + w1 * sg(q1.y) + w2 * sg(q2.x) + w3 * sg(q2.w);
    float dd = w0 * d.x + w1 * d.y + w2 * d.z + w3 * d.w;

    c0 = row16_sum(c0); c0 += swz_xor16(c0);
    c1 = row16_sum(c1); c1 += swz_xor16(c1);
    c2 = row16_sum(c2); c2 += swz_xor16(c2);
    dd = row16_sum(dd); dd += swz_xor16(dd);

    if (llane == 0 && ray < n_rays) {
        out_color[(size_t)ray * 3 + 0] = c0;
        out_color[(size_t)ray * 3 + 1] = c1;
        out_color[(size_t)ray * 3 + 2] = c2;
        out_depth[ray] = dd;
    }
}

// Issue one tile's loads (5 x dwordx4 per lane, all fully independent).
#define LOADT(D, S, Q0, Q1, Q2, t)                                           \
    do {                                                                     \
        int r_  = (t) * (NBLK * 8) + ray_in_grid;                            \
        int cr_ = (r_ < n_rays) ? r_ : (n_rays - 1);                         \
        size_t b_ = (size_t)cr_ * N_SAMPLES;                                 \
        D = *reinterpret_cast<const float4*>(depth + b_ + 4 * llane);        \
        S = *reinterpret_cast<const float4*>(sigma + b_ + 4 * llane);        \
        const float* rb_ = rgb + (size_t)cr_ * (N_SAMPLES * 3) + llane * 12; \
        Q0 = *reinterpret_cast<const float4*>(rb_);                          \
        Q1 = *reinterpret_cast<const float4*>(rb_ + 4);                      \
        Q2 = *reinterpret_cast<const float4*>(rb_ + 8);                      \
    } while (0)

__global__ __launch_bounds__(256) void volrender_kernel(
    const float* __restrict__ depth,
    const float* __restrict__ rgb,
    const float* __restrict__ sigma,
    float* __restrict__ out_color,
    float* __restrict__ out_depth,
    int n_rays)
{
    const int tid   = threadIdx.x;
    const int llane = tid & 31;          // lane within the ray's 32-lane group
    const int slot  = tid >> 5;          // 0..7: ray slot within block
    const int ray_in_grid = blockIdx.x * 8 + slot;

    const int iters = (n_rays + NBLK * 8 - 1) / (NBLK * 8);   // 8 for 131072

    float4 dA, sA, qA0, qA1, qA2;
    float4 dB, sB, qB0, qB1, qB2;

    LOADT(dA, sA, qA0, qA1, qA2, 0);

    for (int t = 0; t < iters; t += 2) {
        if (t + 1 < iters) LOADT(dB, sB, qB0, qB1, qB2, t + 1);
        compute_store(dA, sA, qA0, qA1, qA2,
                      t * (NBLK * 8) + ray_in_grid, n_rays, llane,
                      out_color, out_depth);
        if (t + 2 < iters) LOADT(dA, sA, qA0, qA1, qA2, t + 2);
        if (t + 1 < iters)
            compute_store(dB, sB, qB0, qB1, qB2,
                          (t + 1) * (NBLK * 8) + ray_in_grid, n_rays, llane,
                          out_color, out_depth);
    }
}

extern "C" void kernel_launch(void* const* d_in, const int* in_sizes, int n_in,
                              void* d_out, int out_size, void* d_ws, size_t ws_size,
                              hipStream_t stream)
{
    const float* depth = (const float*)d_in[0];
    const float* rgb   = (const float*)d_in[1];
    const float* sigma = (const float*)d_in[2];

    const int n_rays = in_sizes[0] / N_SAMPLES;

    float* out_color = (float*)d_out;                      // [n_rays, 3]
    float* out_depth = out_color + (size_t)n_rays * 3;     // [n_rays, 1]

    hipLaunchKernelGGL(volrender_kernel, dim3(NBLK), dim3(256), 0, stream,
                       depth, rgb, sigma, out_color, out_depth, n_rays);
}

// Round 8
// 60.897 us; speedup vs baseline: 1.0542x; 1.0542x over previous
//
#include <hip/hip_runtime.h>

#define N_SAMPLES 128

// ROOFLINE-CANDIDATE RESTORE of the measured-best variant (round 2, 61.44 us).
// Evidence trail: shfl-scan (61.4), DPP-scan (61.9), DPP+LDS-staged rgb (61.8),
// 16-lane coarsened (71.0), persistent+double-buffer (64.2). The plateau at
// ~61.5 us == 322 MB / 61.5 us ~= 5.2 TB/s read-stream equilibrium with ~50%
// of bytes served by Infinity Cache; no pipe saturated -> platform read-path
// bandwidth floor for this 3-stream float32 mix.

__global__ __launch_bounds__(256) void volrender_kernel(
    const float* __restrict__ depth,
    const float* __restrict__ rgb,
    const float* __restrict__ sigma,
    float* __restrict__ out_color,
    float* __restrict__ out_depth,
    int n_rays)
{
    // 32 lanes per ray, 4 samples per lane. 2 rays per wave, 8 rays per block.
    const int tid   = threadIdx.x;
    const int llane = tid & 31;               // lane within the ray's 32-lane group
    const int ray   = blockIdx.x * 8 + (tid >> 5);
    if (ray >= n_rays) return;

    const size_t base = (size_t)ray * N_SAMPLES;

    float4 d = *reinterpret_cast<const float4*>(depth + base + 4 * llane);
    float4 s = *reinterpret_cast<const float4*>(sigma + base + 4 * llane);

    // delta[i] = d[i+1] - d[i]; sample 127 padded with 1e10
    float dnext  = __shfl_down(d.x, 1, 32);
    float delta0 = d.y - d.x;
    float delta1 = d.z - d.y;
    float delta2 = d.w - d.z;
    float delta3 = (llane == 31) ? 1e10f : (dnext - d.w);

    const float EPS = 1e-10f;
    float e0 = __expf(-fmaxf(s.x, 0.0f) * delta0);
    float e1 = __expf(-fmaxf(s.y, 0.0f) * delta1);
    float e2 = __expf(-fmaxf(s.z, 0.0f) * delta2);
    float e3 = __expf(-fmaxf(s.w, 0.0f) * delta3);
    float a0 = 1.0f - e0, a1 = 1.0f - e1, a2 = 1.0f - e2, a3 = 1.0f - e3;
    float t0 = e0 + EPS, t1 = e1 + EPS, t2 = e2 + EPS, t3 = e3 + EPS;

    // Inclusive multiplicative scan of per-lane product across 32 lanes
    float p = t0 * t1 * t2 * t3;
#pragma unroll
    for (int off = 1; off < 32; off <<= 1) {
        float v = __shfl_up(p, off, 32);
        if (llane >= off) p *= v;
    }
    float excl = __shfl_up(p, 1, 32);
    if (llane == 0) excl = 1.0f;

    // Per-sample exclusive transmittance prefixes
    float w0 = a0 * excl;
    float pre1 = excl * t0;
    float w1 = a1 * pre1;
    float pre2 = pre1 * t1;
    float w2 = a2 * pre2;
    float w3 = a3 * pre2 * t2;

    // rgb: 12 contiguous floats per lane at ray*384 + 12*llane (16B-aligned)
    const float* rbase = rgb + (size_t)ray * (N_SAMPLES * 3) + llane * 12;
    float4 q0 = *reinterpret_cast<const float4*>(rbase);      // R0 G0 B0 R1
    float4 q1 = *reinterpret_cast<const float4*>(rbase + 4);  // G1 B1 R2 G2
    float4 q2 = *reinterpret_cast<const float4*>(rbase + 8);  // B2 R3 G3 B3

    auto sigmoid = [](float x) { return 1.0f / (1.0f + __expf(-x)); };

    float c0 = w0 * sigmoid(q0.x) + w1 * sigmoid(q0.w) + w2 * sigmoid(q1.z) + w3 * sigmoid(q2.y);
    float c1 = w0 * sigmoid(q0.y) + w1 * sigmoid(q1.x) + w2 * sigmoid(q1.w) + w3 * sigmoid(q2.z);
    float c2 = w0 * sigmoid(q0.z) + w1 * sigmoid(q1.y) + w2 * sigmoid(q2.x) + w3 * sigmoid(q2.w);
    float dd = w0 * d.x + w1 * d.y + w2 * d.z + w3 * d.w;

    // Reduce across the 32-lane group
#pragma unroll
    for (int m = 16; m >= 1; m >>= 1) {
        c0 += __shfl_xor(c0, m, 32);
        c1 += __shfl_xor(c1, m, 32);
        c2 += __shfl_xor(c2, m, 32);
        dd += __shfl_xor(dd, m, 32);
    }

    if (llane == 0) {
        out_color[(size_t)ray * 3 + 0] = c0;
        out_color[(size_t)ray * 3 + 1] = c1;
        out_color[(size_t)ray * 3 + 2] = c2;
        out_depth[ray] = dd;
    }
}

extern "C" void kernel_launch(void* const* d_in, const int* in_sizes, int n_in,
                              void* d_out, int out_size, void* d_ws, size_t ws_size,
                              hipStream_t stream)
{
    const float* depth = (const float*)d_in[0];
    const float* rgb   = (const float*)d_in[1];
    const float* sigma = (const float*)d_in[2];

    const int n_rays = in_sizes[0] / N_SAMPLES;

    float* out_color = (float*)d_out;                      // [n_rays, 3]
    float* out_depth = out_color + (size_t)n_rays * 3;     // [n_rays, 1]

    const int rays_per_block = 8;  // 256 threads, 32 lanes/ray
    const int blocks = (n_rays + rays_per_block - 1) / rays_per_block;

    hipLaunchKernelGGL(volrender_kernel, dim3(blocks), dim3(256), 0, stream,
                       depth, rgb, sigma, out_color, out_depth, n_rays);
}